// Round 2
// baseline (487.271 us; speedup 1.0000x reference)
//
#include <hip/hip_runtime.h>

// out[e,i] = sum_j mat[e,i,j] v[e,j] + bias[e,i],  [mat|bias] = MLP(pos).reshape(32,33)
// Round-3 structure: per block of 256 edges,
//   P[e, col] = h2[e,0:128] @ Wpack[0:128, col]   (col = j*32+i; W3-only)
//   out[e,i]  = sum_{col: i} vext[e,j] * P[e,col] + (b3 mini-GEMM: sum_j v[e,j] b3[i*33+j] + b3[i*33+32])
// Changes vs round-2:
//  - B-fragments read DIRECTLY from global (L2-resident, 264 KB) into registers,
//    3-buffer depth-2 pipeline -> ZERO barriers in the G-loop, waves free-run.
//  - vt built AFTER the transient h1c/h2n stage buffers (overlapping smem) ->
//    LDS 60928 -> 34320 B -> 4 blocks/CU -> 4 waves/SIMD (__launch_bounds__(256,4)).
// ws: Wg2 @0 (270336 B), W2f @270336 (32768 B), b3f @303104 (2048 B), b3c @305152 (128 B)

#define E_TOTAL 262144
#define EPB 256
#define NBLK (E_TOTAL / EPB)

typedef float f32x4 __attribute__((ext_vector_type(4)));
typedef short s8v  __attribute__((ext_vector_type(8)));

__device__ __forceinline__ unsigned short f2bf(float x) {
  unsigned u = __float_as_uint(x);
  u += 0x7fffu + ((u >> 16) & 1u);
  return (unsigned short)(u >> 16);
}

// ---------------- prep: pack W2/W3/b3 into MFMA B-fragment order ----------------
__global__ void prep_pack(const float* __restrict__ W2, const float* __restrict__ W3,
                          const float* __restrict__ b3,
                          unsigned short* __restrict__ Wg2, unsigned short* __restrict__ W2f,
                          unsigned short* __restrict__ b3f, float* __restrict__ b3c) {
  int idx = blockIdx.x * 256 + threadIdx.x;   // 528 blocks cover 135168
  if (idx < 135168) {
    // Wg2[((nn*4+ks)*64 + lane)*8 + jj] : B[k=ks*32+(lane>>4)*8+jj][col]
    // nn is the PERMUTED tile order: nn<33 -> tile 2*nn (ih=0), else tile 2*(nn-33)+1 (ih=1)
    int jj = idx & 7, lane = (idx >> 3) & 63;
    int ksnn = idx >> 9, ks = ksnn & 3, nn = ksnn >> 2;
    int nnt = (nn < 33) ? (2 * nn) : (2 * (nn - 33) + 1);
    int k = ks * 32 + ((lane >> 4) << 3) + jj;
    int col = nnt * 16 + (lane & 15);        // col = j*32 + i
    int i = col & 31, j = col >> 5;
    Wg2[idx] = f2bf(W3[k * 1056 + i * 33 + j]);
  }
  if (idx < 16384) {
    // W2f[((ks*8+nt)*64 + lane)*8 + jj]: n=nt*16+(lane&15), k=ks*32+(lane>>4)*8+jj
    int ks = idx >> 12, nt = (idx >> 9) & 7, l = (idx >> 3) & 63, jj = idx & 7;
    int k = ks * 32 + ((l >> 4) << 3) + jj;
    int n = nt * 16 + (l & 15);
    W2f[idx] = f2bf(W2[k * 128 + n]);
  }
  if (idx < 1024) {
    // b3f[(ih*64+lane)*8+jj]: B[k=j][n=i] = b3[i*33+j], j<32
    int jj = idx & 7, lane = (idx >> 3) & 63, ih = idx >> 9;
    int j = ((lane >> 4) << 3) + jj, i = ih * 16 + (lane & 15);
    b3f[idx] = f2bf(b3[i * 33 + j]);
  }
  if (idx < 32) b3c[idx] = b3[idx * 33 + 32];
}

// ---------------- G-loop helpers (register-resident B, direct from L2) ----------------
__device__ __forceinline__ void tile_load(s8v (&dst)[4], const unsigned short* __restrict__ Wg2,
                                          int n, int lane) {
  // frag ks of tile n: Wg2[(n*4+ks)*512 + lane*8], 16 B/lane, fully coalesced dwordx4
  const s8v* src = (const s8v*)(Wg2 + (size_t)n * 2048 + lane * 8);
#pragma unroll
  for (int ks = 0; ks < 4; ++ks) dst[ks] = src[ks * 64];
}

template <int IH>
__device__ __forceinline__ void tile_compute(const s8v (&bf)[4], const float* __restrict__ vt,
                                             int j, int eoff,
                                             const s8v (&af)[4][4], float (&oa)[2][4][4]) {
  const f32x4 zero4 = {0.f, 0.f, 0.f, 0.f};
  const float* vp = vt + j * 260 + eoff;
#pragma unroll
  for (int m = 0; m < 4; ++m) {
    f32x4 p = __builtin_amdgcn_mfma_f32_16x16x32_bf16(af[m][0], bf[0], zero4, 0, 0, 0);
#pragma unroll
    for (int ks = 1; ks < 4; ++ks)
      p = __builtin_amdgcn_mfma_f32_16x16x32_bf16(af[m][ks], bf[ks], p, 0, 0, 0);
    f32x4 vv = *(const f32x4*)(vp + m * 16);  // broadcast across the 16 lanes of each q-group
#pragma unroll
    for (int r = 0; r < 4; ++r) oa[IH][m][r] += vv[r] * p[r];
  }
}

// ---------------- fused main kernel ----------------
// 256 threads (4 waves), 256 edges/block; wave w owns edges [B0+w*64, B0+w*64+64).
// LDS (overlapped phases):
//   prologue: h2n u16[64][136] @0 (17408), h1c u16[32][136] @17408 (8704)  -> 26112 B
//   G-loop:   vt f32[33][260] @0 (34320 B)
// static smem = 34320 B -> 4 blocks/CU -> 4 waves/SIMD.
__global__ __launch_bounds__(256, 4) void fnn_fused(
    const float* __restrict__ pos_i, const float* __restrict__ pos_j,
    const float* __restrict__ vj, const float* __restrict__ W1,
    const float* __restrict__ b1, const float* __restrict__ b2,
    const unsigned short* __restrict__ W2f, const unsigned short* __restrict__ Wg2,
    const unsigned short* __restrict__ b3f, const float* __restrict__ b3c,
    float* __restrict__ out) {
  __shared__ __attribute__((aligned(16))) char smem[34320];
  float* vt = (float*)smem;                                  // [33][260], G-loop phase
  unsigned short* h2n = (unsigned short*)smem;               // [64][136], prologue phase
  unsigned short* h1c = (unsigned short*)(smem + 17408);     // [32][136], prologue phase

  const int tid = threadIdx.x;
  const int w = tid >> 6, lane = tid & 63, q = lane >> 4, ln = lane & 15;
  const int B0 = blockIdx.x * EPB;
  const int eoff = w * 64 + q * 4;

  // --- out-acc init via b3 mini-GEMM: oa[ih][m][r] = sum_j v[e,j] b3[i*33+j] + b3[i*33+32] ---
  float oa[2][4][4];
  {
    s8v av[4];
#pragma unroll
    for (int m = 0; m < 4; ++m) {
      int e = B0 + w * 64 + m * 16 + ln;
      const float4 va = *(const float4*)(vj + (size_t)e * 32 + q * 8);
      const float4 vb = *(const float4*)(vj + (size_t)e * 32 + q * 8 + 4);
      s8v t;
      t[0] = (short)f2bf(va.x); t[1] = (short)f2bf(va.y);
      t[2] = (short)f2bf(va.z); t[3] = (short)f2bf(va.w);
      t[4] = (short)f2bf(vb.x); t[5] = (short)f2bf(vb.y);
      t[6] = (short)f2bf(vb.z); t[7] = (short)f2bf(vb.w);
      av[m] = t;
    }
#pragma unroll
    for (int ih = 0; ih < 2; ++ih) {
      s8v b3fr = *(const s8v*)(b3f + (ih * 64 + lane) * 8);
      float cbv = b3c[ih * 16 + ln];
      f32x4 ci = {cbv, cbv, cbv, cbv};
#pragma unroll
      for (int m = 0; m < 4; ++m) {
        f32x4 p = __builtin_amdgcn_mfma_f32_16x16x32_bf16(av[m], b3fr, ci, 0, 0, 0);
#pragma unroll
        for (int r = 0; r < 4; ++r) oa[ih][m][r] = p[r];
      }
    }
  }

  // --- W1/b1 register slice: thread owns 8 hidden cols for stage 1 ---
  const int hh0 = (tid & 15) * 8;
  float w1r[4][8], b1r[8];
#pragma unroll
  for (int d = 0; d < 4; ++d)
#pragma unroll
    for (int u = 0; u < 8; ++u) w1r[d][u] = W1[d * 128 + hh0 + u];
#pragma unroll
  for (int u = 0; u < 8; ++u) b1r[u] = b1[hh0 + u];

  // --- stages 1+2 per quarter (64 edges), extract A-frags to registers ---
  s8v af[4][4];
  for (int qtr = 0; qtr < 4; ++qtr) {
    for (int cb = 0; cb < 2; ++cb) {
#pragma unroll
      for (int half = 0; half < 2; ++half) {
        int ee = (tid >> 4) + half * 16;
        int eg = B0 + qtr * 64 + cb * 32 + ee;
        float2 pi = *(const float2*)(pos_i + (size_t)eg * 2);
        float2 pj = *(const float2*)(pos_j + (size_t)eg * 2);
        s8v hv;
#pragma unroll
        for (int u = 0; u < 8; ++u) {
          float o = b1r[u] + pi.x * w1r[0][u] + pi.y * w1r[1][u] +
                    pj.x * w1r[2][u] + pj.y * w1r[3][u];
          hv[u] = (short)f2bf(fmaxf(o, 0.f));
        }
        *(s8v*)&h1c[ee * 136 + hh0] = hv;
      }
      __syncthreads();
#pragma unroll
      for (int s = 0; s < 4; ++s) {
        int tt = w * 4 + s, mt = tt >> 3, nt = tt & 7;
        f32x4 a4 = {0.f, 0.f, 0.f, 0.f};
#pragma unroll
        for (int ks = 0; ks < 4; ++ks) {
          s8v afr = *(const s8v*)&h1c[(mt * 16 + ln) * 136 + ks * 32 + q * 8];
          s8v bfr = *(const s8v*)(W2f + ((ks * 8 + nt) * 64 + lane) * 8);
          a4 = __builtin_amdgcn_mfma_f32_16x16x32_bf16(afr, bfr, a4, 0, 0, 0);
        }
        float b2v = b2[nt * 16 + ln];
        int eb = cb * 32 + mt * 16 + q * 4;
        int kc = nt * 16 + ln;
#pragma unroll
        for (int r = 0; r < 4; ++r)
          h2n[(eb + r) * 136 + kc] = f2bf(fmaxf(a4[r] + b2v, 0.f));
      }
      __syncthreads();
    }
    if (w == qtr) {
#pragma unroll
      for (int m = 0; m < 4; ++m)
#pragma unroll
        for (int ks = 0; ks < 4; ++ks)
          af[m][ks] = *(const s8v*)&h2n[(m * 16 + ln) * 136 + ks * 32 + q * 8];
    }
    __syncthreads();   // extraction reads drained before h2n reuse / vt overwrite
  }

  // --- build vt: vt[j][e] = v[e,j] (f32), row 32 = 1.0 (overwrites h1c/h2n region) ---
  {
    const float* vrow = vj + (size_t)(B0 + tid) * 32;
#pragma unroll
    for (int j4 = 0; j4 < 8; ++j4) {
      float4 vv = *(const float4*)(vrow + j4 * 4);
      vt[(j4 * 4 + 0) * 260 + tid] = vv.x;
      vt[(j4 * 4 + 1) * 260 + tid] = vv.y;
      vt[(j4 * 4 + 2) * 260 + tid] = vv.z;
      vt[(j4 * 4 + 3) * 260 + tid] = vv.w;
    }
    vt[32 * 260 + tid] = 1.0f;
  }

  // prime the B pipeline while the vt barrier settles (tiles 0,1 from L2)
  s8v bA[4], bB[4], bC[4];
  tile_load(bA, Wg2, 0, lane);
  tile_load(bB, Wg2, 1, lane);
  __syncthreads();

  // --- G-loop: 66 flat tiles, 3-buffer depth-2 register pipeline, ZERO barriers.
  //     Tail loads for n=66,67 overread into the W2f region of the same workspace
  //     (bytes 270336..278528 < 305280) — harmless, values unused.
#pragma unroll 1
  for (int c = 0; c < 11; ++c) {
    const int n = c * 3;                 // half 0: tiles 0..32, j = n
    tile_load(bC, Wg2, n + 2, lane);
    tile_compute<0>(bA, vt, n + 0, eoff, af, oa);
    tile_load(bA, Wg2, n + 3, lane);
    tile_compute<0>(bB, vt, n + 1, eoff, af, oa);
    tile_load(bB, Wg2, n + 4, lane);
    tile_compute<0>(bC, vt, n + 2, eoff, af, oa);
  }
#pragma unroll 1
  for (int c = 0; c < 11; ++c) {
    const int n = 33 + c * 3;            // half 1: tiles 33..65, j = n-33
    tile_load(bC, Wg2, n + 2, lane);
    tile_compute<1>(bA, vt, n - 33 + 0, eoff, af, oa);
    tile_load(bA, Wg2, n + 3, lane);
    tile_compute<1>(bB, vt, n - 33 + 1, eoff, af, oa);
    tile_load(bB, Wg2, n + 4, lane);
    tile_compute<1>(bC, vt, n - 33 + 2, eoff, af, oa);
  }

  // --- epilogue: out[e,i] f32 ---
#pragma unroll
  for (int m = 0; m < 4; ++m)
#pragma unroll
    for (int ih = 0; ih < 2; ++ih)
#pragma unroll
      for (int r = 0; r < 4; ++r) {
        int e = B0 + w * 64 + m * 16 + q * 4 + r;
        out[(size_t)e * 32 + ih * 16 + ln] = oa[ih][m][r];
      }
}

extern "C" void kernel_launch(void* const* d_in, const int* in_sizes, int n_in,
                              void* d_out, int out_size, void* d_ws, size_t ws_size,
                              hipStream_t stream) {
  const float* pos_i = (const float*)d_in[0];
  const float* pos_j = (const float*)d_in[1];
  const float* vj    = (const float*)d_in[2];
  const float* W1    = (const float*)d_in[3];
  const float* b1    = (const float*)d_in[4];
  const float* W2    = (const float*)d_in[5];
  const float* b2    = (const float*)d_in[6];
  const float* W3    = (const float*)d_in[7];
  const float* b3    = (const float*)d_in[8];
  float* outp = (float*)d_out;

  unsigned short* Wg2 = (unsigned short*)d_ws;
  unsigned short* W2f = (unsigned short*)((char*)d_ws + 270336);
  unsigned short* b3f = (unsigned short*)((char*)d_ws + 303104);
  float*          b3c = (float*)((char*)d_ws + 305152);

  prep_pack<<<528, 256, 0, stream>>>(W2, W3, b3, Wg2, W2f, b3f, b3c);
  fnn_fused<<<NBLK, 256, 0, stream>>>(pos_i, pos_j, vj, W1, b1, b2, W2f, Wg2, b3f, b3c, outp);
}

// Round 3
// 291.194 us; speedup vs baseline: 1.6734x; 1.6734x over previous
//
#include <hip/hip_runtime.h>

// out[e,i] = sum_j mat[e,i,j] v[e,j] + bias[e,i],  [mat|bias] = MLP(pos).reshape(32,33)
// Round-4 structure: per block of 256 edges,
//   P[e, col] = h2[e,0:128] @ Wpack[0:128, col]   (col = j*32+i; W3-only)
//   out[e,i]  = sum_{col: i} vext[e,j] * P[e,col] + (b3 mini-GEMM)
// Changes vs round-2 (round-3 direct-to-reg spilled -> reverted to LDS-staged B):
//  - vt built AFTER transient h1c/h2n (overlapping smem) -> LDS 60928 -> 50704 B
//  - B staged in 2-tile chunks (8 KB buf, double-buffered) via global_load_lds
//    width=16 (async, zero registers, no ds_write roundtrip)
//  - 3 blocks/CU (launch_bounds(256,3)): LDS 160/50.7 = 3, VGPR cap 168 (~130 used)
// ws: Wg2 @0 (270336 B), W2f @270336 (32768 B), b3f @303104 (2048 B), b3c @305152 (128 B)

#define E_TOTAL 262144
#define EPB 256
#define NBLK (E_TOTAL / EPB)

typedef float f32x4 __attribute__((ext_vector_type(4)));
typedef short s8v  __attribute__((ext_vector_type(8)));
typedef unsigned int u32;

__device__ __forceinline__ unsigned short f2bf(float x) {
  unsigned u = __float_as_uint(x);
  u += 0x7fffu + ((u >> 16) & 1u);
  return (unsigned short)(u >> 16);
}

__device__ __forceinline__ void ld16_g2l(const void* g, void* l) {
  __builtin_amdgcn_global_load_lds((const __attribute__((address_space(1))) u32*)g,
                                   (__attribute__((address_space(3))) u32*)l, 16, 0, 0);
}

// ---------------- prep: pack W2/W3/b3 into MFMA B-fragment order ----------------
__global__ void prep_pack(const float* __restrict__ W2, const float* __restrict__ W3,
                          const float* __restrict__ b3,
                          unsigned short* __restrict__ Wg2, unsigned short* __restrict__ W2f,
                          unsigned short* __restrict__ b3f, float* __restrict__ b3c) {
  int idx = blockIdx.x * 256 + threadIdx.x;   // 528 blocks cover 135168
  if (idx < 135168) {
    // Wg2[((nn*4+ks)*64 + lane)*8 + jj] : B[k=ks*32+(lane>>4)*8+jj][col]
    // nn is the PERMUTED tile order: nn<33 -> tile 2*nn (ih=0), else tile 2*(nn-33)+1 (ih=1)
    int jj = idx & 7, lane = (idx >> 3) & 63;
    int ksnn = idx >> 9, ks = ksnn & 3, nn = ksnn >> 2;
    int nnt = (nn < 33) ? (2 * nn) : (2 * (nn - 33) + 1);
    int k = ks * 32 + ((lane >> 4) << 3) + jj;
    int col = nnt * 16 + (lane & 15);        // col = j*32 + i
    int i = col & 31, j = col >> 5;
    Wg2[idx] = f2bf(W3[k * 1056 + i * 33 + j]);
  }
  if (idx < 16384) {
    // W2f[((ks*8+nt)*64 + lane)*8 + jj]: n=nt*16+(lane&15), k=ks*32+(lane>>4)*8+jj
    int ks = idx >> 12, nt = (idx >> 9) & 7, l = (idx >> 3) & 63, jj = idx & 7;
    int k = ks * 32 + ((l >> 4) << 3) + jj;
    int n = nt * 16 + (l & 15);
    W2f[idx] = f2bf(W2[k * 128 + n]);
  }
  if (idx < 1024) {
    // b3f[(ih*64+lane)*8+jj]: B[k=j][n=i] = b3[i*33+j], j<32
    int jj = idx & 7, lane = (idx >> 3) & 63, ih = idx >> 9;
    int j = ((lane >> 4) << 3) + jj, i = ih * 16 + (lane & 15);
    b3f[idx] = f2bf(b3[i * 33 + j]);
  }
  if (idx < 32) b3c[idx] = b3[idx * 33 + 32];
}

// ---------------- G-loop helpers ----------------
// stage chunk c (tiles 2c, 2c+1; 4096 u16 = 8192 B) into Bb buffer `buf`.
// LDS dest is wave-uniform base + lane*16 (global_load_lds semantics).
__device__ __forceinline__ void stage_chunk(const unsigned short* __restrict__ Wg2,
                                            char* BbChar, int c, int buf, int tid, int w) {
  const unsigned short* src = Wg2 + (size_t)c * 4096 + tid * 8;
  char* ldsb = BbChar + buf * 8192 + w * 1024;   // wave-uniform
  ld16_g2l(src, ldsb);
  ld16_g2l(src + 2048, ldsb + 4096);
}

template <int IH>
__device__ __forceinline__ void tile_compute(const unsigned short* __restrict__ buf, int t,
                                             const float* __restrict__ vt,
                                             int j, int lane, int eoff,
                                             const s8v (&af)[4][4], float (&oa)[2][4][4]) {
  const f32x4 zero4 = {0.f, 0.f, 0.f, 0.f};
  s8v bfr[4];
#pragma unroll
  for (int ks = 0; ks < 4; ++ks)
    bfr[ks] = *(const s8v*)&buf[(t * 4 + ks) * 512 + lane * 8];
  const float* vp = vt + j * 260 + eoff;
#pragma unroll
  for (int m = 0; m < 4; ++m) {
    f32x4 p = __builtin_amdgcn_mfma_f32_16x16x32_bf16(af[m][0], bfr[0], zero4, 0, 0, 0);
#pragma unroll
    for (int ks = 1; ks < 4; ++ks)
      p = __builtin_amdgcn_mfma_f32_16x16x32_bf16(af[m][ks], bfr[ks], p, 0, 0, 0);
    f32x4 vv = *(const f32x4*)(vp + m * 16);  // broadcast within each 16-lane group
#pragma unroll
    for (int r = 0; r < 4; ++r) oa[IH][m][r] += vv[r] * p[r];
  }
}

// ---------------- fused main kernel ----------------
// 256 threads (4 waves), 256 edges/block; wave w owns edges [B0+w*64, B0+w*64+64).
// LDS (overlapped phases):
//   prologue: h2n u16[64][136] @0 (17408), h1c u16[32][136] @17408 (8704)
//   G-loop:   vt f32[33][260] @0 (34320) | Bb u16[2][4096] @34320 (16384)
// static smem = 50704 B -> 3 blocks/CU, VGPR cap 168 at 3 waves/SIMD.
__global__ __launch_bounds__(256, 3) void fnn_fused(
    const float* __restrict__ pos_i, const float* __restrict__ pos_j,
    const float* __restrict__ vj, const float* __restrict__ W1,
    const float* __restrict__ b1, const float* __restrict__ b2,
    const unsigned short* __restrict__ W2f, const unsigned short* __restrict__ Wg2,
    const unsigned short* __restrict__ b3f, const float* __restrict__ b3c,
    float* __restrict__ out) {
  __shared__ __attribute__((aligned(16))) char smem[50704];
  float* vt = (float*)smem;                                  // [33][260], G-loop phase
  unsigned short* h2n = (unsigned short*)smem;               // [64][136], prologue phase
  unsigned short* h1c = (unsigned short*)(smem + 17408);     // [32][136], prologue phase
  unsigned short* Bb  = (unsigned short*)(smem + 34320);     // [2][4096], G-loop phase
  char* BbChar = smem + 34320;

  const int tid = threadIdx.x;
  const int w = tid >> 6, lane = tid & 63, q = lane >> 4, ln = lane & 15;
  const int B0 = blockIdx.x * EPB;
  const int eoff = w * 64 + q * 4;

  // prime chunk 0 immediately (Bb region untouched by prologue; prep_pack already done)
  stage_chunk(Wg2, BbChar, 0, 0, tid, w);

  // --- out-acc init via b3 mini-GEMM: oa[ih][m][r] = sum_j v[e,j] b3[i*33+j] + b3[i*33+32] ---
  float oa[2][4][4];
  {
    s8v av[4];
#pragma unroll
    for (int m = 0; m < 4; ++m) {
      int e = B0 + w * 64 + m * 16 + ln;
      const float4 va = *(const float4*)(vj + (size_t)e * 32 + q * 8);
      const float4 vb = *(const float4*)(vj + (size_t)e * 32 + q * 8 + 4);
      s8v t;
      t[0] = (short)f2bf(va.x); t[1] = (short)f2bf(va.y);
      t[2] = (short)f2bf(va.z); t[3] = (short)f2bf(va.w);
      t[4] = (short)f2bf(vb.x); t[5] = (short)f2bf(vb.y);
      t[6] = (short)f2bf(vb.z); t[7] = (short)f2bf(vb.w);
      av[m] = t;
    }
#pragma unroll
    for (int ih = 0; ih < 2; ++ih) {
      s8v b3fr = *(const s8v*)(b3f + (ih * 64 + lane) * 8);
      float cbv = b3c[ih * 16 + ln];
      f32x4 ci = {cbv, cbv, cbv, cbv};
#pragma unroll
      for (int m = 0; m < 4; ++m) {
        f32x4 p = __builtin_amdgcn_mfma_f32_16x16x32_bf16(av[m], b3fr, ci, 0, 0, 0);
#pragma unroll
        for (int r = 0; r < 4; ++r) oa[ih][m][r] = p[r];
      }
    }
  }

  // --- W1/b1 register slice: thread owns 8 hidden cols for stage 1 ---
  const int hh0 = (tid & 15) * 8;
  float w1r[4][8], b1r[8];
#pragma unroll
  for (int d = 0; d < 4; ++d)
#pragma unroll
    for (int u = 0; u < 8; ++u) w1r[d][u] = W1[d * 128 + hh0 + u];
#pragma unroll
  for (int u = 0; u < 8; ++u) b1r[u] = b1[hh0 + u];

  // --- stages 1+2 per quarter (64 edges), extract A-frags to registers ---
  s8v af[4][4];
  for (int qtr = 0; qtr < 4; ++qtr) {
    for (int cb = 0; cb < 2; ++cb) {
#pragma unroll
      for (int half = 0; half < 2; ++half) {
        int ee = (tid >> 4) + half * 16;
        int eg = B0 + qtr * 64 + cb * 32 + ee;
        float2 pi = *(const float2*)(pos_i + (size_t)eg * 2);
        float2 pj = *(const float2*)(pos_j + (size_t)eg * 2);
        s8v hv;
#pragma unroll
        for (int u = 0; u < 8; ++u) {
          float o = b1r[u] + pi.x * w1r[0][u] + pi.y * w1r[1][u] +
                    pj.x * w1r[2][u] + pj.y * w1r[3][u];
          hv[u] = (short)f2bf(fmaxf(o, 0.f));
        }
        *(s8v*)&h1c[ee * 136 + hh0] = hv;
      }
      __syncthreads();
#pragma unroll
      for (int s = 0; s < 4; ++s) {
        int tt = w * 4 + s, mt = tt >> 3, nt = tt & 7;
        f32x4 a4 = {0.f, 0.f, 0.f, 0.f};
#pragma unroll
        for (int ks = 0; ks < 4; ++ks) {
          s8v afr = *(const s8v*)&h1c[(mt * 16 + ln) * 136 + ks * 32 + q * 8];
          s8v bfr = *(const s8v*)(W2f + ((ks * 8 + nt) * 64 + lane) * 8);
          a4 = __builtin_amdgcn_mfma_f32_16x16x32_bf16(afr, bfr, a4, 0, 0, 0);
        }
        float b2v = b2[nt * 16 + ln];
        int eb = cb * 32 + mt * 16 + q * 4;
        int kc = nt * 16 + ln;
#pragma unroll
        for (int r = 0; r < 4; ++r)
          h2n[(eb + r) * 136 + kc] = f2bf(fmaxf(a4[r] + b2v, 0.f));
      }
      __syncthreads();
    }
    if (w == qtr) {
#pragma unroll
      for (int m = 0; m < 4; ++m)
#pragma unroll
        for (int ks = 0; ks < 4; ++ks)
          af[m][ks] = *(const s8v*)&h2n[(m * 16 + ln) * 136 + ks * 32 + q * 8];
    }
    __syncthreads();   // extraction reads drained before h2n reuse / vt overwrite
  }

  // --- build vt: vt[j][e] = v[e,j] (f32), row 32 = 1.0 (overwrites h1c/h2n region) ---
  {
    const float* vrow = vj + (size_t)(B0 + tid) * 32;
#pragma unroll
    for (int j4 = 0; j4 < 8; ++j4) {
      float4 vv = *(const float4*)(vrow + j4 * 4);
      vt[(j4 * 4 + 0) * 260 + tid] = vv.x;
      vt[(j4 * 4 + 1) * 260 + tid] = vv.y;
      vt[(j4 * 4 + 2) * 260 + tid] = vv.z;
      vt[(j4 * 4 + 3) * 260 + tid] = vv.w;
    }
    vt[32 * 260 + tid] = 1.0f;
  }
  __syncthreads();   // vt ready; barrier drain also guarantees chunk 0 staged

  // --- G-loop: 33 chunks x 2 tiles, double-buffered async staging, 1 barrier/chunk ---
  // flat tile n: ih = n>=33, j = ih ? n-33 : n.  Chunk c = tiles {2c, 2c+1}.
#pragma unroll 1
  for (int c = 0; c < 16; ++c) {        // tiles 0..31, all IH=0
    const unsigned short* buf = Bb + (c & 1) * 4096;
    stage_chunk(Wg2, BbChar, c + 1, (c + 1) & 1, tid, w);
    tile_compute<0>(buf, 0, vt, 2 * c,     lane, eoff, af, oa);
    tile_compute<0>(buf, 1, vt, 2 * c + 1, lane, eoff, af, oa);
    __syncthreads();
  }
  {                                     // straddle chunk 16: tile 32 (IH0,j=32), tile 33 (IH1,j=0)
    const unsigned short* buf = Bb;     // 16&1 == 0
    stage_chunk(Wg2, BbChar, 17, 1, tid, w);
    tile_compute<0>(buf, 0, vt, 32, lane, eoff, af, oa);
    tile_compute<1>(buf, 1, vt, 0,  lane, eoff, af, oa);
    __syncthreads();
  }
#pragma unroll 1
  for (int c = 17; c < 33; ++c) {       // tiles 34..65, all IH=1; j = 2c-33, 2c-32
    const unsigned short* buf = Bb + (c & 1) * 4096;
    if (c + 1 < 33) stage_chunk(Wg2, BbChar, c + 1, (c + 1) & 1, tid, w);
    tile_compute<1>(buf, 0, vt, 2 * c - 33, lane, eoff, af, oa);
    tile_compute<1>(buf, 1, vt, 2 * c - 32, lane, eoff, af, oa);
    __syncthreads();
  }

  // --- epilogue: out[e,i] f32 ---
#pragma unroll
  for (int m = 0; m < 4; ++m)
#pragma unroll
    for (int ih = 0; ih < 2; ++ih)
#pragma unroll
      for (int r = 0; r < 4; ++r) {
        int e = B0 + w * 64 + m * 16 + q * 4 + r;
        out[(size_t)e * 32 + ih * 16 + ln] = oa[ih][m][r];
      }
}

extern "C" void kernel_launch(void* const* d_in, const int* in_sizes, int n_in,
                              void* d_out, int out_size, void* d_ws, size_t ws_size,
                              hipStream_t stream) {
  const float* pos_i = (const float*)d_in[0];
  const float* pos_j = (const float*)d_in[1];
  const float* vj    = (const float*)d_in[2];
  const float* W1    = (const float*)d_in[3];
  const float* b1    = (const float*)d_in[4];
  const float* W2    = (const float*)d_in[5];
  const float* b2    = (const float*)d_in[6];
  const float* W3    = (const float*)d_in[7];
  const float* b3    = (const float*)d_in[8];
  float* outp = (float*)d_out;

  unsigned short* Wg2 = (unsigned short*)d_ws;
  unsigned short* W2f = (unsigned short*)((char*)d_ws + 270336);
  unsigned short* b3f = (unsigned short*)((char*)d_ws + 303104);
  float*          b3c = (float*)((char*)d_ws + 305152);

  prep_pack<<<528, 256, 0, stream>>>(W2, W3, b3, Wg2, W2f, b3f, b3c);
  fnn_fused<<<NBLK, 256, 0, stream>>>(pos_i, pos_j, vj, W1, b1, b2, W2f, Wg2, b3f, b3c, outp);
}

// Round 4
// 185.271 us; speedup vs baseline: 2.6300x; 1.5717x over previous
//
#include <hip/hip_runtime.h>

// out[e,i] = sum_j mat[e,i,j] v[e,j] + bias[e,i],  [mat|bias] = MLP(pos).reshape(32,33)
// Round-5: identical structure to round-4 EXCEPT __launch_bounds__(256,2).
// Empirical finding (rounds 0/2/3): hipcc allocates VGPRs for 2x the declared
// min-waves/EU: arg2=4 -> 64 VGPR, arg2=3 -> 84 VGPR (both spill af/oa to scratch,
// +250..550 MB symmetric FETCH/WRITE). arg2=2 -> 128-VGPR cap, demand ~120, no spill.
// Occupancy is LDS-limited: 50704 B -> 3 blocks/CU = 3 waves/SIMD.
//   P[e, col] = h2[e,0:128] @ Wpack[0:128, col]   (col = j*32+i; W3-only)
//   out[e,i]  = sum_{col: i} vext[e,j] * P[e,col] + (b3 mini-GEMM)
//  - vt built AFTER transient h1c/h2n (overlapping smem) -> LDS 60928 -> 50704 B
//  - B staged in 2-tile chunks (8 KB buf, double-buffered) via global_load_lds width=16
// ws: Wg2 @0 (270336 B), W2f @270336 (32768 B), b3f @303104 (2048 B), b3c @305152 (128 B)

#define E_TOTAL 262144
#define EPB 256
#define NBLK (E_TOTAL / EPB)

typedef float f32x4 __attribute__((ext_vector_type(4)));
typedef short s8v  __attribute__((ext_vector_type(8)));
typedef unsigned int u32;

__device__ __forceinline__ unsigned short f2bf(float x) {
  unsigned u = __float_as_uint(x);
  u += 0x7fffu + ((u >> 16) & 1u);
  return (unsigned short)(u >> 16);
}

__device__ __forceinline__ void ld16_g2l(const void* g, void* l) {
  __builtin_amdgcn_global_load_lds((const __attribute__((address_space(1))) u32*)g,
                                   (__attribute__((address_space(3))) u32*)l, 16, 0, 0);
}

// ---------------- prep: pack W2/W3/b3 into MFMA B-fragment order ----------------
__global__ void prep_pack(const float* __restrict__ W2, const float* __restrict__ W3,
                          const float* __restrict__ b3,
                          unsigned short* __restrict__ Wg2, unsigned short* __restrict__ W2f,
                          unsigned short* __restrict__ b3f, float* __restrict__ b3c) {
  int idx = blockIdx.x * 256 + threadIdx.x;   // 528 blocks cover 135168
  if (idx < 135168) {
    // Wg2[((nn*4+ks)*64 + lane)*8 + jj] : B[k=ks*32+(lane>>4)*8+jj][col]
    // nn is the PERMUTED tile order: nn<33 -> tile 2*nn (ih=0), else tile 2*(nn-33)+1 (ih=1)
    int jj = idx & 7, lane = (idx >> 3) & 63;
    int ksnn = idx >> 9, ks = ksnn & 3, nn = ksnn >> 2;
    int nnt = (nn < 33) ? (2 * nn) : (2 * (nn - 33) + 1);
    int k = ks * 32 + ((lane >> 4) << 3) + jj;
    int col = nnt * 16 + (lane & 15);        // col = j*32 + i
    int i = col & 31, j = col >> 5;
    Wg2[idx] = f2bf(W3[k * 1056 + i * 33 + j]);
  }
  if (idx < 16384) {
    // W2f[((ks*8+nt)*64 + lane)*8 + jj]: n=nt*16+(lane&15), k=ks*32+(lane>>4)*8+jj
    int ks = idx >> 12, nt = (idx >> 9) & 7, l = (idx >> 3) & 63, jj = idx & 7;
    int k = ks * 32 + ((l >> 4) << 3) + jj;
    int n = nt * 16 + (l & 15);
    W2f[idx] = f2bf(W2[k * 128 + n]);
  }
  if (idx < 1024) {
    // b3f[(ih*64+lane)*8+jj]: B[k=j][n=i] = b3[i*33+j], j<32
    int jj = idx & 7, lane = (idx >> 3) & 63, ih = idx >> 9;
    int j = ((lane >> 4) << 3) + jj, i = ih * 16 + (lane & 15);
    b3f[idx] = f2bf(b3[i * 33 + j]);
  }
  if (idx < 32) b3c[idx] = b3[idx * 33 + 32];
}

// ---------------- G-loop helpers ----------------
// stage chunk c (tiles 2c, 2c+1; 4096 u16 = 8192 B) into Bb buffer `buf`.
// LDS dest is wave-uniform base + lane*16 (global_load_lds semantics).
__device__ __forceinline__ void stage_chunk(const unsigned short* __restrict__ Wg2,
                                            char* BbChar, int c, int buf, int tid, int w) {
  const unsigned short* src = Wg2 + (size_t)c * 4096 + tid * 8;
  char* ldsb = BbChar + buf * 8192 + w * 1024;   // wave-uniform
  ld16_g2l(src, ldsb);
  ld16_g2l(src + 2048, ldsb + 4096);
}

template <int IH>
__device__ __forceinline__ void tile_compute(const unsigned short* __restrict__ buf, int t,
                                             const float* __restrict__ vt,
                                             int j, int lane, int eoff,
                                             const s8v (&af)[4][4], float (&oa)[2][4][4]) {
  const f32x4 zero4 = {0.f, 0.f, 0.f, 0.f};
  s8v bfr[4];
#pragma unroll
  for (int ks = 0; ks < 4; ++ks)
    bfr[ks] = *(const s8v*)&buf[(t * 4 + ks) * 512 + lane * 8];
  const float* vp = vt + j * 260 + eoff;
#pragma unroll
  for (int m = 0; m < 4; ++m) {
    f32x4 p = __builtin_amdgcn_mfma_f32_16x16x32_bf16(af[m][0], bfr[0], zero4, 0, 0, 0);
#pragma unroll
    for (int ks = 1; ks < 4; ++ks)
      p = __builtin_amdgcn_mfma_f32_16x16x32_bf16(af[m][ks], bfr[ks], p, 0, 0, 0);
    f32x4 vv = *(const f32x4*)(vp + m * 16);  // broadcast within each 16-lane group
#pragma unroll
    for (int r = 0; r < 4; ++r) oa[IH][m][r] += vv[r] * p[r];
  }
}

// ---------------- fused main kernel ----------------
// 256 threads (4 waves), 256 edges/block; wave w owns edges [B0+w*64, B0+w*64+64).
// LDS (overlapped phases):
//   prologue: h2n u16[64][136] @0 (17408), h1c u16[32][136] @17408 (8704)
//   G-loop:   vt f32[33][260] @0 (34320) | Bb u16[2][4096] @34320 (16384)
// static smem = 50704 B -> 3 blocks/CU (LDS-limited); VGPR cap 128 (demand ~120).
__global__ __launch_bounds__(256, 2) void fnn_fused(
    const float* __restrict__ pos_i, const float* __restrict__ pos_j,
    const float* __restrict__ vj, const float* __restrict__ W1,
    const float* __restrict__ b1, const float* __restrict__ b2,
    const unsigned short* __restrict__ W2f, const unsigned short* __restrict__ Wg2,
    const unsigned short* __restrict__ b3f, const float* __restrict__ b3c,
    float* __restrict__ out) {
  __shared__ __attribute__((aligned(16))) char smem[50704];
  float* vt = (float*)smem;                                  // [33][260], G-loop phase
  unsigned short* h2n = (unsigned short*)smem;               // [64][136], prologue phase
  unsigned short* h1c = (unsigned short*)(smem + 17408);     // [32][136], prologue phase
  unsigned short* Bb  = (unsigned short*)(smem + 34320);     // [2][4096], G-loop phase
  char* BbChar = smem + 34320;

  const int tid = threadIdx.x;
  const int w = tid >> 6, lane = tid & 63, q = lane >> 4, ln = lane & 15;
  const int B0 = blockIdx.x * EPB;
  const int eoff = w * 64 + q * 4;

  // prime chunk 0 immediately (Bb region untouched by prologue; prep_pack already done)
  stage_chunk(Wg2, BbChar, 0, 0, tid, w);

  // --- out-acc init via b3 mini-GEMM: oa[ih][m][r] = sum_j v[e,j] b3[i*33+j] + b3[i*33+32] ---
  float oa[2][4][4];
  {
    s8v av[4];
#pragma unroll
    for (int m = 0; m < 4; ++m) {
      int e = B0 + w * 64 + m * 16 + ln;
      const float4 va = *(const float4*)(vj + (size_t)e * 32 + q * 8);
      const float4 vb = *(const float4*)(vj + (size_t)e * 32 + q * 8 + 4);
      s8v t;
      t[0] = (short)f2bf(va.x); t[1] = (short)f2bf(va.y);
      t[2] = (short)f2bf(va.z); t[3] = (short)f2bf(va.w);
      t[4] = (short)f2bf(vb.x); t[5] = (short)f2bf(vb.y);
      t[6] = (short)f2bf(vb.z); t[7] = (short)f2bf(vb.w);
      av[m] = t;
    }
#pragma unroll
    for (int ih = 0; ih < 2; ++ih) {
      s8v b3fr = *(const s8v*)(b3f + (ih * 64 + lane) * 8);
      float cbv = b3c[ih * 16 + ln];
      f32x4 ci = {cbv, cbv, cbv, cbv};
#pragma unroll
      for (int m = 0; m < 4; ++m) {
        f32x4 p = __builtin_amdgcn_mfma_f32_16x16x32_bf16(av[m], b3fr, ci, 0, 0, 0);
#pragma unroll
        for (int r = 0; r < 4; ++r) oa[ih][m][r] = p[r];
      }
    }
  }

  // --- W1/b1 register slice: thread owns 8 hidden cols for stage 1 ---
  const int hh0 = (tid & 15) * 8;
  float w1r[4][8], b1r[8];
#pragma unroll
  for (int d = 0; d < 4; ++d)
#pragma unroll
    for (int u = 0; u < 8; ++u) w1r[d][u] = W1[d * 128 + hh0 + u];
#pragma unroll
  for (int u = 0; u < 8; ++u) b1r[u] = b1[hh0 + u];

  // --- stages 1+2 per quarter (64 edges), extract A-frags to registers ---
  s8v af[4][4];
  for (int qtr = 0; qtr < 4; ++qtr) {
    for (int cb = 0; cb < 2; ++cb) {
#pragma unroll
      for (int half = 0; half < 2; ++half) {
        int ee = (tid >> 4) + half * 16;
        int eg = B0 + qtr * 64 + cb * 32 + ee;
        float2 pi = *(const float2*)(pos_i + (size_t)eg * 2);
        float2 pj = *(const float2*)(pos_j + (size_t)eg * 2);
        s8v hv;
#pragma unroll
        for (int u = 0; u < 8; ++u) {
          float o = b1r[u] + pi.x * w1r[0][u] + pi.y * w1r[1][u] +
                    pj.x * w1r[2][u] + pj.y * w1r[3][u];
          hv[u] = (short)f2bf(fmaxf(o, 0.f));
        }
        *(s8v*)&h1c[ee * 136 + hh0] = hv;
      }
      __syncthreads();
#pragma unroll
      for (int s = 0; s < 4; ++s) {
        int tt = w * 4 + s, mt = tt >> 3, nt = tt & 7;
        f32x4 a4 = {0.f, 0.f, 0.f, 0.f};
#pragma unroll
        for (int ks = 0; ks < 4; ++ks) {
          s8v afr = *(const s8v*)&h1c[(mt * 16 + ln) * 136 + ks * 32 + q * 8];
          s8v bfr = *(const s8v*)(W2f + ((ks * 8 + nt) * 64 + lane) * 8);
          a4 = __builtin_amdgcn_mfma_f32_16x16x32_bf16(afr, bfr, a4, 0, 0, 0);
        }
        float b2v = b2[nt * 16 + ln];
        int eb = cb * 32 + mt * 16 + q * 4;
        int kc = nt * 16 + ln;
#pragma unroll
        for (int r = 0; r < 4; ++r)
          h2n[(eb + r) * 136 + kc] = f2bf(fmaxf(a4[r] + b2v, 0.f));
      }
      __syncthreads();
    }
    if (w == qtr) {
#pragma unroll
      for (int m = 0; m < 4; ++m)
#pragma unroll
        for (int ks = 0; ks < 4; ++ks)
          af[m][ks] = *(const s8v*)&h2n[(m * 16 + ln) * 136 + ks * 32 + q * 8];
    }
    __syncthreads();   // extraction reads drained before h2n reuse / vt overwrite
  }

  // --- build vt: vt[j][e] = v[e,j] (f32), row 32 = 1.0 (overwrites h1c/h2n region) ---
  {
    const float* vrow = vj + (size_t)(B0 + tid) * 32;
#pragma unroll
    for (int j4 = 0; j4 < 8; ++j4) {
      float4 vv = *(const float4*)(vrow + j4 * 4);
      vt[(j4 * 4 + 0) * 260 + tid] = vv.x;
      vt[(j4 * 4 + 1) * 260 + tid] = vv.y;
      vt[(j4 * 4 + 2) * 260 + tid] = vv.z;
      vt[(j4 * 4 + 3) * 260 + tid] = vv.w;
    }
    vt[32 * 260 + tid] = 1.0f;
  }
  __syncthreads();   // vt ready; barrier drain also guarantees chunk 0 staged

  // --- G-loop: 33 chunks x 2 tiles, double-buffered async staging, 1 barrier/chunk ---
  // flat tile n: ih = n>=33, j = ih ? n-33 : n.  Chunk c = tiles {2c, 2c+1}.
#pragma unroll 1
  for (int c = 0; c < 16; ++c) {        // tiles 0..31, all IH=0
    const unsigned short* buf = Bb + (c & 1) * 4096;
    stage_chunk(Wg2, BbChar, c + 1, (c + 1) & 1, tid, w);
    tile_compute<0>(buf, 0, vt, 2 * c,     lane, eoff, af, oa);
    tile_compute<0>(buf, 1, vt, 2 * c + 1, lane, eoff, af, oa);
    __syncthreads();
  }
  {                                     // straddle chunk 16: tile 32 (IH0,j=32), tile 33 (IH1,j=0)
    const unsigned short* buf = Bb;     // 16&1 == 0
    stage_chunk(Wg2, BbChar, 17, 1, tid, w);
    tile_compute<0>(buf, 0, vt, 32, lane, eoff, af, oa);
    tile_compute<1>(buf, 1, vt, 0,  lane, eoff, af, oa);
    __syncthreads();
  }
#pragma unroll 1
  for (int c = 17; c < 33; ++c) {       // tiles 34..65, all IH=1; j = 2c-33, 2c-32
    const unsigned short* buf = Bb + (c & 1) * 4096;
    if (c + 1 < 33) stage_chunk(Wg2, BbChar, c + 1, (c + 1) & 1, tid, w);
    tile_compute<1>(buf, 0, vt, 2 * c - 33, lane, eoff, af, oa);
    tile_compute<1>(buf, 1, vt, 2 * c - 32, lane, eoff, af, oa);
    __syncthreads();
  }

  // --- epilogue: out[e,i] f32 ---
#pragma unroll
  for (int m = 0; m < 4; ++m)
#pragma unroll
    for (int ih = 0; ih < 2; ++ih)
#pragma unroll
      for (int r = 0; r < 4; ++r) {
        int e = B0 + w * 64 + m * 16 + q * 4 + r;
        out[(size_t)e * 32 + ih * 16 + ln] = oa[ih][m][r];
      }
}

extern "C" void kernel_launch(void* const* d_in, const int* in_sizes, int n_in,
                              void* d_out, int out_size, void* d_ws, size_t ws_size,
                              hipStream_t stream) {
  const float* pos_i = (const float*)d_in[0];
  const float* pos_j = (const float*)d_in[1];
  const float* vj    = (const float*)d_in[2];
  const float* W1    = (const float*)d_in[3];
  const float* b1    = (const float*)d_in[4];
  const float* W2    = (const float*)d_in[5];
  const float* b2    = (const float*)d_in[6];
  const float* W3    = (const float*)d_in[7];
  const float* b3    = (const float*)d_in[8];
  float* outp = (float*)d_out;

  unsigned short* Wg2 = (unsigned short*)d_ws;
  unsigned short* W2f = (unsigned short*)((char*)d_ws + 270336);
  unsigned short* b3f = (unsigned short*)((char*)d_ws + 303104);
  float*          b3c = (float*)((char*)d_ws + 305152);

  prep_pack<<<528, 256, 0, stream>>>(W2, W3, b3, Wg2, W2f, b3f, b3c);
  fnn_fused<<<NBLK, 256, 0, stream>>>(pos_i, pos_j, vj, W1, b1, b2, W2f, Wg2, b3f, b3c, outp);
}

// Round 5
// 184.769 us; speedup vs baseline: 2.6372x; 1.0027x over previous
//
#include <hip/hip_runtime.h>

// out[e,i] = sum_j mat[e,i,j] v[e,j] + bias[e,i],  [mat|bias] = MLP(pos).reshape(32,33)
// Round-6: barrier-free G-loop with register-resident B (single-buffer prefetch).
// Key facts: Wg2 (264 KB) is L2-resident -> per-wave direct loads are cheap;
// vt is PER-WAVE self-contained (wave w writes/reads only cols [w*64,w*64+64)),
// so after the prologue's last barrier there are NO cross-wave deps at all.
// LDS = vt only (34320 B) -> 4 blocks/CU; VGPR target <=128 ((256,2), round-4
// empirics: arg2=2 -> 128 cap, 124 used). Grid 1024 = 4 blocks/CU of work ->
// exactly one residency round, no scheduling tail.
// Register budget: af 64 + oa 32 + bf 16 + misc ~12 -> ~124.
//   P[e, col] = h2[e,0:128] @ Wpack[0:128, col]   (col = j*32+i; W3-only)
//   out[e,i]  = sum_{col: i} vext[e,j] * P[e,col] + (b3 mini-GEMM)
// ws: Wg2 @0 (270336 B), W2f @270336 (32768 B), b3f @303104 (2048 B), b3c @305152 (128 B)

#define E_TOTAL 262144
#define EPB 256
#define NBLK (E_TOTAL / EPB)

typedef float f32x4 __attribute__((ext_vector_type(4)));
typedef short s8v  __attribute__((ext_vector_type(8)));

__device__ __forceinline__ unsigned short f2bf(float x) {
  unsigned u = __float_as_uint(x);
  u += 0x7fffu + ((u >> 16) & 1u);
  return (unsigned short)(u >> 16);
}

// ---------------- prep: pack W2/W3/b3 into MFMA B-fragment order ----------------
__global__ void prep_pack(const float* __restrict__ W2, const float* __restrict__ W3,
                          const float* __restrict__ b3,
                          unsigned short* __restrict__ Wg2, unsigned short* __restrict__ W2f,
                          unsigned short* __restrict__ b3f, float* __restrict__ b3c) {
  int idx = blockIdx.x * 256 + threadIdx.x;   // 528 blocks cover 135168
  if (idx < 135168) {
    // Wg2[((nn*4+ks)*64 + lane)*8 + jj] : B[k=ks*32+(lane>>4)*8+jj][col]
    // nn is the PERMUTED tile order: nn<33 -> tile 2*nn (ih=0), else tile 2*(nn-33)+1 (ih=1)
    int jj = idx & 7, lane = (idx >> 3) & 63;
    int ksnn = idx >> 9, ks = ksnn & 3, nn = ksnn >> 2;
    int nnt = (nn < 33) ? (2 * nn) : (2 * (nn - 33) + 1);
    int k = ks * 32 + ((lane >> 4) << 3) + jj;
    int col = nnt * 16 + (lane & 15);        // col = j*32 + i
    int i = col & 31, j = col >> 5;
    Wg2[idx] = f2bf(W3[k * 1056 + i * 33 + j]);
  }
  if (idx < 16384) {
    // W2f[((ks*8+nt)*64 + lane)*8 + jj]: n=nt*16+(lane&15), k=ks*32+(lane>>4)*8+jj
    int ks = idx >> 12, nt = (idx >> 9) & 7, l = (idx >> 3) & 63, jj = idx & 7;
    int k = ks * 32 + ((l >> 4) << 3) + jj;
    int n = nt * 16 + (l & 15);
    W2f[idx] = f2bf(W2[k * 128 + n]);
  }
  if (idx < 1024) {
    // b3f[(ih*64+lane)*8+jj]: B[k=j][n=i] = b3[i*33+j], j<32
    int jj = idx & 7, lane = (idx >> 3) & 63, ih = idx >> 9;
    int j = ((lane >> 4) << 3) + jj, i = ih * 16 + (lane & 15);
    b3f[idx] = f2bf(b3[i * 33 + j]);
  }
  if (idx < 32) b3c[idx] = b3[idx * 33 + 32];
}

// ---------------- G-loop helpers (register-resident B, direct from L2) ----------------
__device__ __forceinline__ void tile_load(s8v (&dst)[4], const unsigned short* __restrict__ Wg2,
                                          int n, int lane) {
  // frag ks of tile n: Wg2[(n*4+ks)*512 + lane*8], 16 B/lane, fully coalesced dwordx4;
  // 4 loads share one base, imm offsets 0/1024/2048/3072.
  const s8v* src = (const s8v*)(Wg2 + (size_t)n * 2048 + lane * 8);
#pragma unroll
  for (int ks = 0; ks < 4; ++ks) dst[ks] = src[ks * 64];
}

template <int IH>
__device__ __forceinline__ void tile_compute(const s8v (&bf)[4], const float* __restrict__ vt,
                                             int j, int eoff,
                                             const s8v (&af)[4][4], float (&oa)[2][4][4]) {
  const f32x4 zero4 = {0.f, 0.f, 0.f, 0.f};
  const float* vp = vt + j * 260 + eoff;
#pragma unroll
  for (int m = 0; m < 4; ++m) {
    f32x4 p = __builtin_amdgcn_mfma_f32_16x16x32_bf16(af[m][0], bf[0], zero4, 0, 0, 0);
#pragma unroll
    for (int ks = 1; ks < 4; ++ks)
      p = __builtin_amdgcn_mfma_f32_16x16x32_bf16(af[m][ks], bf[ks], p, 0, 0, 0);
    f32x4 vv = *(const f32x4*)(vp + m * 16);  // 16-lane broadcast, conflict-free
#pragma unroll
    for (int r = 0; r < 4; ++r) oa[IH][m][r] += vv[r] * p[r];
  }
}

// ---------------- fused main kernel ----------------
// 256 threads (4 waves), 256 edges/block; wave w owns edges [B0+w*64, B0+w*64+64).
// LDS (overlapped phases):
//   prologue: h2n u16[64][136] @0 (17408), h1c u16[32][136] @17408 (8704)
//   G-loop:   vt f32[33][260] @0 (34320)
// static smem = 34320 B -> 4 blocks/CU by LDS; VGPR cap 128 -> 4 waves/SIMD.
__global__ __launch_bounds__(256, 2) void fnn_fused(
    const float* __restrict__ pos_i, const float* __restrict__ pos_j,
    const float* __restrict__ vj, const float* __restrict__ W1,
    const float* __restrict__ b1, const float* __restrict__ b2,
    const unsigned short* __restrict__ W2f, const unsigned short* __restrict__ Wg2,
    const unsigned short* __restrict__ b3f, const float* __restrict__ b3c,
    float* __restrict__ out) {
  __shared__ __attribute__((aligned(16))) char smem[34320];
  float* vt = (float*)smem;                                  // [33][260], G-loop phase
  unsigned short* h2n = (unsigned short*)smem;               // [64][136], prologue phase
  unsigned short* h1c = (unsigned short*)(smem + 17408);     // [32][136], prologue phase

  const int tid = threadIdx.x;
  const int w = tid >> 6, lane = tid & 63, q = lane >> 4, ln = lane & 15;
  const int B0 = blockIdx.x * EPB;
  const int eoff = w * 64 + q * 4;

  // --- out-acc init via b3 mini-GEMM: oa[ih][m][r] = sum_j v[e,j] b3[i*33+j] + b3[i*33+32] ---
  float oa[2][4][4];
  {
    s8v av[4];
#pragma unroll
    for (int m = 0; m < 4; ++m) {
      int e = B0 + w * 64 + m * 16 + ln;
      const float4 va = *(const float4*)(vj + (size_t)e * 32 + q * 8);
      const float4 vb = *(const float4*)(vj + (size_t)e * 32 + q * 8 + 4);
      s8v t;
      t[0] = (short)f2bf(va.x); t[1] = (short)f2bf(va.y);
      t[2] = (short)f2bf(va.z); t[3] = (short)f2bf(va.w);
      t[4] = (short)f2bf(vb.x); t[5] = (short)f2bf(vb.y);
      t[6] = (short)f2bf(vb.z); t[7] = (short)f2bf(vb.w);
      av[m] = t;
    }
#pragma unroll
    for (int ih = 0; ih < 2; ++ih) {
      s8v b3fr = *(const s8v*)(b3f + (ih * 64 + lane) * 8);
      float cbv = b3c[ih * 16 + ln];
      f32x4 ci = {cbv, cbv, cbv, cbv};
#pragma unroll
      for (int m = 0; m < 4; ++m) {
        f32x4 p = __builtin_amdgcn_mfma_f32_16x16x32_bf16(av[m], b3fr, ci, 0, 0, 0);
#pragma unroll
        for (int r = 0; r < 4; ++r) oa[ih][m][r] = p[r];
      }
    }
  }

  // --- W1/b1 register slice: thread owns 8 hidden cols for stage 1 ---
  const int hh0 = (tid & 15) * 8;
  float w1r[4][8], b1r[8];
#pragma unroll
  for (int d = 0; d < 4; ++d)
#pragma unroll
    for (int u = 0; u < 8; ++u) w1r[d][u] = W1[d * 128 + hh0 + u];
#pragma unroll
  for (int u = 0; u < 8; ++u) b1r[u] = b1[hh0 + u];

  // --- stages 1+2 per quarter (64 edges), extract A-frags to registers ---
  s8v af[4][4];
  for (int qtr = 0; qtr < 4; ++qtr) {
    for (int cb = 0; cb < 2; ++cb) {
#pragma unroll
      for (int half = 0; half < 2; ++half) {
        int ee = (tid >> 4) + half * 16;
        int eg = B0 + qtr * 64 + cb * 32 + ee;
        float2 pi = *(const float2*)(pos_i + (size_t)eg * 2);
        float2 pj = *(const float2*)(pos_j + (size_t)eg * 2);
        s8v hv;
#pragma unroll
        for (int u = 0; u < 8; ++u) {
          float o = b1r[u] + pi.x * w1r[0][u] + pi.y * w1r[1][u] +
                    pj.x * w1r[2][u] + pj.y * w1r[3][u];
          hv[u] = (short)f2bf(fmaxf(o, 0.f));
        }
        *(s8v*)&h1c[ee * 136 + hh0] = hv;
      }
      __syncthreads();
#pragma unroll
      for (int s = 0; s < 4; ++s) {
        int tt = w * 4 + s, mt = tt >> 3, nt = tt & 7;
        f32x4 a4 = {0.f, 0.f, 0.f, 0.f};
#pragma unroll
        for (int ks = 0; ks < 4; ++ks) {
          s8v afr = *(const s8v*)&h1c[(mt * 16 + ln) * 136 + ks * 32 + q * 8];
          s8v bfr = *(const s8v*)(W2f + ((ks * 8 + nt) * 64 + lane) * 8);
          a4 = __builtin_amdgcn_mfma_f32_16x16x32_bf16(afr, bfr, a4, 0, 0, 0);
        }
        float b2v = b2[nt * 16 + ln];
        int eb = cb * 32 + mt * 16 + q * 4;
        int kc = nt * 16 + ln;
#pragma unroll
        for (int r = 0; r < 4; ++r)
          h2n[(eb + r) * 136 + kc] = f2bf(fmaxf(a4[r] + b2v, 0.f));
      }
      __syncthreads();
    }
    if (w == qtr) {
#pragma unroll
      for (int m = 0; m < 4; ++m)
#pragma unroll
        for (int ks = 0; ks < 4; ++ks)
          af[m][ks] = *(const s8v*)&h2n[(m * 16 + ln) * 136 + ks * 32 + q * 8];
    }
    __syncthreads();   // last cross-wave dep: h2n reads drained before vt overwrite
  }

  // --- prime B tile 0 (register buffer) while vt is being built ---
  s8v bf[4];
  tile_load(bf, Wg2, 0, lane);

  // --- build vt: vt[j][e] = v[e,j] (f32), row 32 = 1.0 (overwrites h1c/h2n region) ---
  // Wave w writes ONLY columns [w*64, w*64+64) and reads ONLY those columns in the
  // G-loop -> no cross-wave dependency -> NO barrier needed from here on.
  {
    const float* vrow = vj + (size_t)(B0 + tid) * 32;
#pragma unroll
    for (int j4 = 0; j4 < 8; ++j4) {
      float4 vv = *(const float4*)(vrow + j4 * 4);
      vt[(j4 * 4 + 0) * 260 + tid] = vv.x;
      vt[(j4 * 4 + 1) * 260 + tid] = vv.y;
      vt[(j4 * 4 + 2) * 260 + tid] = vv.z;
      vt[(j4 * 4 + 3) * 260 + tid] = vv.w;
    }
    vt[32 * 260 + tid] = 1.0f;
  }

  // --- G-loop: 66 flat tiles, single-buffer prefetch (load t+1 after compute t),
  //     ZERO barriers; compiler's register-dep vmcnt does the counting.
  //     Tail load n=66 overreads into W2f region (byte 270336..274432 < 305280) — unused.
#pragma unroll 1
  for (int n = 0; n < 33; ++n) {        // tiles 0..32, IH=0, j = n
    tile_compute<0>(bf, vt, n, eoff, af, oa);
    tile_load(bf, Wg2, n + 1, lane);
  }
#pragma unroll 1
  for (int n = 33; n < 66; ++n) {       // tiles 33..65, IH=1, j = n-33
    tile_compute<1>(bf, vt, n - 33, eoff, af, oa);
    tile_load(bf, Wg2, n + 1, lane);
  }

  // --- epilogue: out[e,i] f32 ---
#pragma unroll
  for (int m = 0; m < 4; ++m)
#pragma unroll
    for (int ih = 0; ih < 2; ++ih)
#pragma unroll
      for (int r = 0; r < 4; ++r) {
        int e = B0 + w * 64 + m * 16 + q * 4 + r;
        out[(size_t)e * 32 + ih * 16 + ln] = oa[ih][m][r];
      }
}

extern "C" void kernel_launch(void* const* d_in, const int* in_sizes, int n_in,
                              void* d_out, int out_size, void* d_ws, size_t ws_size,
                              hipStream_t stream) {
  const float* pos_i = (const float*)d_in[0];
  const float* pos_j = (const float*)d_in[1];
  const float* vj    = (const float*)d_in[2];
  const float* W1    = (const float*)d_in[3];
  const float* b1    = (const float*)d_in[4];
  const float* W2    = (const float*)d_in[5];
  const float* b2    = (const float*)d_in[6];
  const float* W3    = (const float*)d_in[7];
  const float* b3    = (const float*)d_in[8];
  float* outp = (float*)d_out;

  unsigned short* Wg2 = (unsigned short*)d_ws;
  unsigned short* W2f = (unsigned short*)((char*)d_ws + 270336);
  unsigned short* b3f = (unsigned short*)((char*)d_ws + 303104);
  float*          b3c = (float*)((char*)d_ws + 305152);

  prep_pack<<<528, 256, 0, stream>>>(W2, W3, b3, Wg2, W2f, b3f, b3c);
  fnn_fused<<<NBLK, 256, 0, stream>>>(pos_i, pos_j, vj, W1, b1, b2, W2f, Wg2, b3f, b3c, outp);
}